// Round 7
// baseline (152.543 us; speedup 1.0000x reference)
//
#include <hip/hip_runtime.h>

#define NN 512
#define AA 512
#define BB 32
#define CC 16
#define BC 512            // B*C
#define OUTW 544          // A+B
#define LOG2E 1.44269504088896340736f

constexpr int G_ROWS = 8;
constexpr int G_COLS = 64;
constexpr int G_KSPL = 8;
constexpr int G_KLEN = AA / G_KSPL;  // 64

constexpr int NT     = 32;   // 512/16 row-tiles
constexpr int TR     = 16;   // tile rows
constexpr int NTILES = NT * (NT + 1) / 2;  // 528 triangular tile pairs
constexpr int GRID   = 512;  // == guaranteed co-resident capacity at 2 blocks/CU

union SMem {
    struct {
        float xsT[AA][G_ROWS];                 // 16 KB
        float red[G_KSPL][G_COLS][G_ROWS + 1]; // 18.4 KB
    } p1;
    struct {
        float redI[4][TR][32];                 // 8 KB
        float redJ[4][TR][32];                 // 8 KB
    } p2;
};

// ---- producer: gemm slice (8 rows x 64 cols of M), x-copy, -1 init. Round-3 proven code.
__device__ __forceinline__ void produce_slice(SMem& sm, int bx, int t,
                                              const float* __restrict__ x,
                                              const float* __restrict__ T,
                                              float* __restrict__ M,
                                              float* __restrict__ out) {
    const int i0 = (bx >> 3) * G_ROWS;
    const int c0 = (bx & 7) * G_COLS;
    const int kq = t >> 6;
    const int c  = t & 63;

    {
        const int r  = t & 7;
        const int k0 = (t >> 3) * 8;
        const float4 v0 = *(const float4*)(x + (size_t)(i0 + r) * AA + k0);
        const float4 v1 = *(const float4*)(x + (size_t)(i0 + r) * AA + k0 + 4);
        sm.p1.xsT[k0 + 0][r] = v0.x; sm.p1.xsT[k0 + 1][r] = v0.y;
        sm.p1.xsT[k0 + 2][r] = v0.z; sm.p1.xsT[k0 + 3][r] = v0.w;
        sm.p1.xsT[k0 + 4][r] = v1.x; sm.p1.xsT[k0 + 5][r] = v1.y;
        sm.p1.xsT[k0 + 6][r] = v1.z; sm.p1.xsT[k0 + 7][r] = v1.w;
    }
    __syncthreads();

    float acc[G_ROWS];
#pragma unroll
    for (int r = 0; r < G_ROWS; ++r) acc[r] = 0.f;

    const float* Tp = T + (size_t)(kq * G_KLEN) * BC + c0 + c;
#pragma unroll 8
    for (int kk = 0; kk < G_KLEN; ++kk) {
        const float tv = Tp[(size_t)kk * BC];
        const int k = kq * G_KLEN + kk;
        const float4 xa = *(const float4*)&sm.p1.xsT[k][0];
        const float4 xb = *(const float4*)&sm.p1.xsT[k][4];
        acc[0] = fmaf(xa.x, tv, acc[0]);
        acc[1] = fmaf(xa.y, tv, acc[1]);
        acc[2] = fmaf(xa.z, tv, acc[2]);
        acc[3] = fmaf(xa.w, tv, acc[3]);
        acc[4] = fmaf(xb.x, tv, acc[4]);
        acc[5] = fmaf(xb.y, tv, acc[5]);
        acc[6] = fmaf(xb.z, tv, acc[6]);
        acc[7] = fmaf(xb.w, tv, acc[7]);
    }

#pragma unroll
    for (int r = 0; r < G_ROWS; ++r) sm.p1.red[kq][c][r] = acc[r];
    __syncthreads();

    {
        const int r  = t >> 6;
        const int cc = t & 63;
        float s = 0.f;
#pragma unroll
        for (int q = 0; q < G_KSPL; ++q) s += sm.p1.red[q][cc][r];
        M[(size_t)(i0 + r) * BC + c0 + cc] = s * LOG2E;  // pre-scale for exp2
        out[(size_t)(i0 + r) * OUTW + c0 + cc] = x[(size_t)(i0 + r) * AA + c0 + cc];
    }
    if ((bx & 7) == 0 && t < G_ROWS * BB) {
        out[(size_t)(i0 + (t >> 5)) * OUTW + AA + (t & 31)] = -1.0f;
    }
}

// ---- consumer: one triangular 16x16 tile pair. Round-6 proven body + spin-wait.
__device__ __forceinline__ void consume_tile(SMem& sm, int tile, int t,
                                             const float* __restrict__ M,
                                             float* __restrict__ out,
                                             unsigned int* cnt) {
    int rem = tile, I = 0;
    while (rem >= NT - I) { rem -= NT - I; ++I; }
    const int J = I + rem;
    const int i0 = I * TR, j0 = J * TR;
    const bool diag = (I == J);

    // wait until both tile-rows of M are produced & agent-visible
    if (t == 0) {
        while (__hip_atomic_load(&cnt[I], __ATOMIC_ACQUIRE, __HIP_MEMORY_SCOPE_AGENT) < 16u)
            __builtin_amdgcn_s_sleep(2);
        while (__hip_atomic_load(&cnt[J], __ATOMIC_ACQUIRE, __HIP_MEMORY_SCOPE_AGENT) < 16u)
            __builtin_amdgcn_s_sleep(2);
    }
    __syncthreads();   // also protects SMem reuse between phases/tiles

    const int b  = t & 31;
    const int ig = (t >> 5) & 3;
    const int jg = t >> 7;

    float mi[4][CC];
#pragma unroll
    for (int p = 0; p < 4; ++p) {
        const float4* src = (const float4*)(M + (size_t)(i0 + ig * 4 + p) * BC + b * CC);
        const float4 v0 = src[0], v1 = src[1], v2 = src[2], v3 = src[3];
        mi[p][0]  = v0.x; mi[p][1]  = v0.y; mi[p][2]  = v0.z; mi[p][3]  = v0.w;
        mi[p][4]  = v1.x; mi[p][5]  = v1.y; mi[p][6]  = v1.z; mi[p][7]  = v1.w;
        mi[p][8]  = v2.x; mi[p][9]  = v2.y; mi[p][10] = v2.z; mi[p][11] = v2.w;
        mi[p][12] = v3.x; mi[p][13] = v3.y; mi[p][14] = v3.z; mi[p][15] = v3.w;
    }

    float accI[4] = {0.f, 0.f, 0.f, 0.f};
    float accJ[4] = {0.f, 0.f, 0.f, 0.f};

#pragma unroll
    for (int q = 0; q < 4; ++q) {
        const int j = j0 + jg * 4 + q;
        const float4* src = (const float4*)(M + (size_t)j * BC + b * CC);
        const float4 m0 = src[0], m1 = src[1], m2 = src[2], m3 = src[3];
        const float mj[CC] = {m0.x, m0.y, m0.z, m0.w, m1.x, m1.y, m1.z, m1.w,
                              m2.x, m2.y, m2.z, m2.w, m3.x, m3.y, m3.z, m3.w};
#pragma unroll
        for (int p = 0; p < 4; ++p) {
            float d0 = 0.f, d1 = 0.f, d2 = 0.f, d3 = 0.f;
#pragma unroll
            for (int c = 0; c < CC; c += 4) {
                d0 += fabsf(mj[c + 0] - mi[p][c + 0]);   // v_sub + v_add(abs-mod)
                d1 += fabsf(mj[c + 1] - mi[p][c + 1]);
                d2 += fabsf(mj[c + 2] - mi[p][c + 2]);
                d3 += fabsf(mj[c + 3] - mi[p][c + 3]);
            }
            const float c2 = __builtin_amdgcn_exp2f(-((d0 + d1) + (d2 + d3)));
            accI[p] += c2;
            accJ[q] += c2;
        }
    }

#pragma unroll
    for (int p = 0; p < 4; ++p) sm.p2.redI[jg][ig * 4 + p][b] = accI[p];
    if (!diag) {
#pragma unroll
        for (int q = 0; q < 4; ++q) sm.p2.redJ[ig][jg * 4 + q][b] = accJ[q];
    }
    __syncthreads();

    const int rl = t >> 5;
    const int b2 = t & 31;
    {
        const float s = sm.p2.redI[0][rl][b2] + sm.p2.redI[1][rl][b2]
                      + sm.p2.redI[2][rl][b2] + sm.p2.redI[3][rl][b2];
        atomicAdd(out + (size_t)(i0 + rl) * OUTW + AA + b2, s);
    }
    if (!diag) {
        const float s = sm.p2.redJ[0][rl][b2] + sm.p2.redJ[1][rl][b2]
                      + sm.p2.redJ[2][rl][b2] + sm.p2.redJ[3][rl][b2];
        atomicAdd(out + (size_t)(j0 + rl) * OUTW + AA + b2, s);
    }
}

// grid == 512 == co-resident capacity at 2 blocks/CU (enforced below), so every
// block is resident from dispatch; producers never wait -> spin cannot deadlock.
__global__ __launch_bounds__(512, 4) void fused_kernel(const float* __restrict__ x,
                                                       const float* __restrict__ T,
                                                       float* __restrict__ M,
                                                       float* __restrict__ out,
                                                       unsigned int* cnt) {
    __shared__ SMem sm;
    const int bx = blockIdx.x;
    const int t  = threadIdx.x;

    produce_slice(sm, bx, t, x, T, M, out);

    // make this block's M/out stores agent-visible, then signal its tile-row
    __threadfence();
    __syncthreads();
    if (t == 0)
        __hip_atomic_fetch_add(&cnt[bx >> 4], 1u, __ATOMIC_RELEASE, __HIP_MEMORY_SCOPE_AGENT);

    consume_tile(sm, bx, t, M, out, cnt);
    if (bx < NTILES - GRID)                      // blocks 0..15 take the 16 leftover tiles
        consume_tile(sm, GRID + bx, t, M, out, cnt);
}

extern "C" void kernel_launch(void* const* d_in, const int* in_sizes, int n_in,
                              void* d_out, int out_size, void* d_ws, size_t ws_size,
                              hipStream_t stream) {
    const float* x = (const float*)d_in[0];  // (N, A)
    const float* T = (const float*)d_in[1];  // (A, B, C)
    float* out = (float*)d_out;              // (N, A+B)
    float* M   = (float*)d_ws;               // (N, B*C) scratch, 1 MiB
    unsigned int* cnt = (unsigned int*)((char*)d_ws + (size_t)NN * BC * sizeof(float));

    hipMemsetAsync(cnt, 0, NT * sizeof(unsigned int), stream);  // graph-safe memset node
    fused_kernel<<<GRID, 512, 0, stream>>>(x, T, M, out, cnt);
}

// Round 8
// 25.808 us; speedup vs baseline: 5.9107x; 5.9107x over previous
//
#include <hip/hip_runtime.h>

#define NN 512
#define AA 512
#define BB 32
#define CC 16
#define BC 512            // B*C
#define OUTW 544          // A+B
#define LOG2E 1.44269504088896340736f

constexpr int G_ROWS = 8;
constexpr int G_COLS = 128;          // tile cols (2 per thread)
constexpr int G_KSPL = 8;
constexpr int G_KLEN = AA / G_KSPL;  // 64

constexpr int NT   = 32;   // 512/16 row-tiles
constexpr int TR   = 16;   // tile rows

// ---------------- gemm: M = (x @ T) * log2e; out[:, :A] = x; out[:, A:] = -1
// block: 8 rows x 128 cols, 512 thr = 8 kq x 64 c, each thread 2 cols.
// 2 broadcast ds_read_b128 per k-iter feed 16 FMA (was 8) -> LDS instrs/CU halved.
__global__ __launch_bounds__(512) void gemm_kernel(const float* __restrict__ x,
                                                   const float* __restrict__ T,
                                                   float* __restrict__ M,
                                                   float* __restrict__ out) {
    const int bx = blockIdx.x;
    const int i0 = (bx >> 2) * G_ROWS;   // 64 row-groups
    const int c0 = (bx & 3) * G_COLS;    // 4 col-groups
    const int t  = threadIdx.x;
    const int kq = t >> 6;               // 0..7
    const int c  = t & 63;               // col pair base: c0+c and c0+c+64

    __shared__ float xsT[AA][G_ROWS];                    // 16 KB
    __shared__ float red[G_KSPL][G_COLS][G_ROWS + 1];    // 36 KB

    {
        const int r  = t & 7;
        const int k0 = (t >> 3) * 8;
        const float4 v0 = *(const float4*)(x + (size_t)(i0 + r) * AA + k0);
        const float4 v1 = *(const float4*)(x + (size_t)(i0 + r) * AA + k0 + 4);
        xsT[k0 + 0][r] = v0.x; xsT[k0 + 1][r] = v0.y;
        xsT[k0 + 2][r] = v0.z; xsT[k0 + 3][r] = v0.w;
        xsT[k0 + 4][r] = v1.x; xsT[k0 + 5][r] = v1.y;
        xsT[k0 + 6][r] = v1.z; xsT[k0 + 7][r] = v1.w;
    }
    __syncthreads();

    float acc0[G_ROWS], acc1[G_ROWS];
#pragma unroll
    for (int r = 0; r < G_ROWS; ++r) { acc0[r] = 0.f; acc1[r] = 0.f; }

    const float* Tp = T + (size_t)(kq * G_KLEN) * BC + c0 + c;
#pragma unroll 8
    for (int kk = 0; kk < G_KLEN; ++kk) {
        const float tv0 = Tp[(size_t)kk * BC];
        const float tv1 = Tp[(size_t)kk * BC + 64];
        const int k = kq * G_KLEN + kk;
        const float4 xa = *(const float4*)&xsT[k][0];   // broadcast b128
        const float4 xb = *(const float4*)&xsT[k][4];
        acc0[0] = fmaf(xa.x, tv0, acc0[0]);  acc1[0] = fmaf(xa.x, tv1, acc1[0]);
        acc0[1] = fmaf(xa.y, tv0, acc0[1]);  acc1[1] = fmaf(xa.y, tv1, acc1[1]);
        acc0[2] = fmaf(xa.z, tv0, acc0[2]);  acc1[2] = fmaf(xa.z, tv1, acc1[2]);
        acc0[3] = fmaf(xa.w, tv0, acc0[3]);  acc1[3] = fmaf(xa.w, tv1, acc1[3]);
        acc0[4] = fmaf(xb.x, tv0, acc0[4]);  acc1[4] = fmaf(xb.x, tv1, acc1[4]);
        acc0[5] = fmaf(xb.y, tv0, acc0[5]);  acc1[5] = fmaf(xb.y, tv1, acc1[5]);
        acc0[6] = fmaf(xb.z, tv0, acc0[6]);  acc1[6] = fmaf(xb.z, tv1, acc1[6]);
        acc0[7] = fmaf(xb.w, tv0, acc0[7]);  acc1[7] = fmaf(xb.w, tv1, acc1[7]);
    }

#pragma unroll
    for (int r = 0; r < G_ROWS; ++r) {
        red[kq][c][r]      = acc0[r];
        red[kq][c + 64][r] = acc1[r];
    }
    __syncthreads();

    {
        const int r  = t >> 6;   // wave-uniform -> coalesced stores
        const int cc = t & 63;
        float s0 = 0.f, s1 = 0.f;
#pragma unroll
        for (int q = 0; q < G_KSPL; ++q) {
            s0 += red[q][cc][r];
            s1 += red[q][cc + 64][r];
        }
        M[(size_t)(i0 + r) * BC + c0 + cc]      = s0 * LOG2E;
        M[(size_t)(i0 + r) * BC + c0 + cc + 64] = s1 * LOG2E;
        out[(size_t)(i0 + r) * OUTW + c0 + cc]      = x[(size_t)(i0 + r) * AA + c0 + cc];
        out[(size_t)(i0 + r) * OUTW + c0 + cc + 64] = x[(size_t)(i0 + r) * AA + c0 + cc + 64];
    }
    if ((bx & 3) == 0 && t < G_ROWS * BB) {
        out[(size_t)(i0 + (t >> 5)) * OUTW + AA + (t & 31)] = -1.0f;
    }
}

// ---------------- symmetric pairwise over upper-triangle 16x16 row-tile pairs
__global__ __launch_bounds__(512, 4) void pairwise_sym_kernel(const float* __restrict__ M,
                                                              float* __restrict__ out) {
    int rem = blockIdx.x, I = 0;
    while (rem >= NT - I) { rem -= NT - I; ++I; }
    const int J = I + rem;
    const int i0 = I * TR, j0 = J * TR;
    const bool diag = (I == J);

    const int t  = threadIdx.x;
    const int b  = t & 31;
    const int ig = (t >> 5) & 3;
    const int jg = t >> 7;

    float mi[4][CC];
#pragma unroll
    for (int p = 0; p < 4; ++p) {
        const float4* src = (const float4*)(M + (size_t)(i0 + ig * 4 + p) * BC + b * CC);
        const float4 v0 = src[0], v1 = src[1], v2 = src[2], v3 = src[3];
        mi[p][0]  = v0.x; mi[p][1]  = v0.y; mi[p][2]  = v0.z; mi[p][3]  = v0.w;
        mi[p][4]  = v1.x; mi[p][5]  = v1.y; mi[p][6]  = v1.z; mi[p][7]  = v1.w;
        mi[p][8]  = v2.x; mi[p][9]  = v2.y; mi[p][10] = v2.z; mi[p][11] = v2.w;
        mi[p][12] = v3.x; mi[p][13] = v3.y; mi[p][14] = v3.z; mi[p][15] = v3.w;
    }

    float accI[4] = {0.f, 0.f, 0.f, 0.f};
    float accJ[4] = {0.f, 0.f, 0.f, 0.f};

#pragma unroll
    for (int q = 0; q < 4; ++q) {
        const int j = j0 + jg * 4 + q;
        const float4* src = (const float4*)(M + (size_t)j * BC + b * CC);
        const float4 m0 = src[0], m1 = src[1], m2 = src[2], m3 = src[3];
        const float mj[CC] = {m0.x, m0.y, m0.z, m0.w, m1.x, m1.y, m1.z, m1.w,
                              m2.x, m2.y, m2.z, m2.w, m3.x, m3.y, m3.z, m3.w};
#pragma unroll
        for (int p = 0; p < 4; ++p) {
            float d0 = 0.f, d1 = 0.f, d2 = 0.f, d3 = 0.f;
#pragma unroll
            for (int c = 0; c < CC; c += 4) {
                d0 += fabsf(mj[c + 0] - mi[p][c + 0]);   // v_sub + v_add(abs-mod)
                d1 += fabsf(mj[c + 1] - mi[p][c + 1]);
                d2 += fabsf(mj[c + 2] - mi[p][c + 2]);
                d3 += fabsf(mj[c + 3] - mi[p][c + 3]);
            }
            const float c2 = __builtin_amdgcn_exp2f(-((d0 + d1) + (d2 + d3)));
            accI[p] += c2;
            accJ[q] += c2;
        }
    }

    __shared__ float redI[4][TR][32];
    __shared__ float redJ[4][TR][32];
#pragma unroll
    for (int p = 0; p < 4; ++p) redI[jg][ig * 4 + p][b] = accI[p];
    if (!diag) {
#pragma unroll
        for (int q = 0; q < 4; ++q) redJ[ig][jg * 4 + q][b] = accJ[q];
    }
    __syncthreads();

    const int rl = t >> 5;
    const int b2 = t & 31;
    {
        const float s = redI[0][rl][b2] + redI[1][rl][b2]
                      + redI[2][rl][b2] + redI[3][rl][b2];
        atomicAdd(out + (size_t)(i0 + rl) * OUTW + AA + b2, s);
    }
    if (!diag) {
        const float s = redJ[0][rl][b2] + redJ[1][rl][b2]
                      + redJ[2][rl][b2] + redJ[3][rl][b2];
        atomicAdd(out + (size_t)(j0 + rl) * OUTW + AA + b2, s);
    }
}

extern "C" void kernel_launch(void* const* d_in, const int* in_sizes, int n_in,
                              void* d_out, int out_size, void* d_ws, size_t ws_size,
                              hipStream_t stream) {
    const float* x = (const float*)d_in[0];  // (N, A)
    const float* T = (const float*)d_in[1];  // (A, B, C)
    float* out = (float*)d_out;              // (N, A+B)
    float* M   = (float*)d_ws;               // (N, B*C) scratch, 1 MiB

    gemm_kernel<<<256, 512, 0, stream>>>(x, T, M, out);
    pairwise_sym_kernel<<<NT * (NT + 1) / 2, 512, 0, stream>>>(M, out);
}

// Round 9
// 25.480 us; speedup vs baseline: 5.9868x; 1.0129x over previous
//
#include <hip/hip_runtime.h>

#define NN 512
#define AA 512
#define BB 32
#define CC 16
#define BC 512            // B*C
#define OUTW 544          // A+B
#define LOG2E 1.44269504088896340736f

constexpr int G_ROWS = 8;
constexpr int G_COLS = 128;          // tile cols (2 per thread: c and c+64)
constexpr int G_KSPL = 8;
constexpr int G_KLEN = AA / G_KSPL;  // 64

constexpr int NT   = 32;   // 512/16 row-tiles
constexpr int TR   = 16;   // tile rows

// ---------------- gemm: M = (x @ T) * log2e; out[:, :A] = x; out[:, A:] = -1
// block: 8 rows x 128 cols, 512 thr = 8 kq-waves x 64 c. x comes in via the
// SCALAR pipe (wave-uniform rows x uniform k -> s_load), no LDS staging at all:
// inner loop = 2 vector T-loads + 16 fmac with SGPR x-operand.
__global__ __launch_bounds__(512) void gemm_kernel(const float* __restrict__ x,
                                                   const float* __restrict__ T,
                                                   float* __restrict__ M,
                                                   float* __restrict__ out) {
    const int bx = blockIdx.x;
    const int i0 = (bx >> 2) * G_ROWS;   // 64 row-groups
    const int c0 = (bx & 3) * G_COLS;    // 4 col-groups
    const int t  = threadIdx.x;
    // each wave (64 lanes) is exactly one kq chunk -> force into SGPR
    const int kq = __builtin_amdgcn_readfirstlane(t >> 6);   // 0..7
    const int c  = t & 63;               // cols c0+c and c0+c+64

    __shared__ float red[G_KSPL][G_COLS][G_ROWS + 1];    // 36 KB, stride 9 (odd) -> 2-way max

    float acc0[G_ROWS], acc1[G_ROWS];
#pragma unroll
    for (int r = 0; r < G_ROWS; ++r) { acc0[r] = 0.f; acc1[r] = 0.f; }

    // wave-uniform x base for this kq chunk (all indices SGPR-computable)
    const float* xu = x + (size_t)i0 * AA + kq * G_KLEN;
    const float* Tp = T + (size_t)(kq * G_KLEN) * BC + c0 + c;

#pragma unroll 8
    for (int kk = 0; kk < G_KLEN; ++kk) {
        const float tv0 = Tp[(size_t)kk * BC];        // coalesced vector loads
        const float tv1 = Tp[(size_t)kk * BC + 64];
#pragma unroll
        for (int r = 0; r < G_ROWS; ++r) {
            const float xv = xu[(size_t)r * AA + kk]; // wave-uniform -> s_load
            acc0[r] = fmaf(xv, tv0, acc0[r]);
            acc1[r] = fmaf(xv, tv1, acc1[r]);
        }
    }

#pragma unroll
    for (int r = 0; r < G_ROWS; ++r) {
        red[kq][c][r]      = acc0[r];
        red[kq][c + 64][r] = acc1[r];
    }
    __syncthreads();

    {
        const int r  = t >> 6;   // wave-uniform -> coalesced stores
        const int cc = t & 63;
        float s0 = 0.f, s1 = 0.f;
#pragma unroll
        for (int q = 0; q < G_KSPL; ++q) {
            s0 += red[q][cc][r];
            s1 += red[q][cc + 64][r];
        }
        M[(size_t)(i0 + r) * BC + c0 + cc]      = s0 * LOG2E;
        M[(size_t)(i0 + r) * BC + c0 + cc + 64] = s1 * LOG2E;
        out[(size_t)(i0 + r) * OUTW + c0 + cc]      = x[(size_t)(i0 + r) * AA + c0 + cc];
        out[(size_t)(i0 + r) * OUTW + c0 + cc + 64] = x[(size_t)(i0 + r) * AA + c0 + cc + 64];
    }
    if ((bx & 3) == 0 && t < G_ROWS * BB) {
        out[(size_t)(i0 + (t >> 5)) * OUTW + AA + (t & 31)] = -1.0f;
    }
}

// ---------------- symmetric pairwise over upper-triangle 16x16 row-tile pairs
__global__ __launch_bounds__(512, 4) void pairwise_sym_kernel(const float* __restrict__ M,
                                                              float* __restrict__ out) {
    int rem = blockIdx.x, I = 0;
    while (rem >= NT - I) { rem -= NT - I; ++I; }
    const int J = I + rem;
    const int i0 = I * TR, j0 = J * TR;
    const bool diag = (I == J);

    const int t  = threadIdx.x;
    const int b  = t & 31;
    const int ig = (t >> 5) & 3;
    const int jg = t >> 7;

    float mi[4][CC];
#pragma unroll
    for (int p = 0; p < 4; ++p) {
        const float4* src = (const float4*)(M + (size_t)(i0 + ig * 4 + p) * BC + b * CC);
        const float4 v0 = src[0], v1 = src[1], v2 = src[2], v3 = src[3];
        mi[p][0]  = v0.x; mi[p][1]  = v0.y; mi[p][2]  = v0.z; mi[p][3]  = v0.w;
        mi[p][4]  = v1.x; mi[p][5]  = v1.y; mi[p][6]  = v1.z; mi[p][7]  = v1.w;
        mi[p][8]  = v2.x; mi[p][9]  = v2.y; mi[p][10] = v2.z; mi[p][11] = v2.w;
        mi[p][12] = v3.x; mi[p][13] = v3.y; mi[p][14] = v3.z; mi[p][15] = v3.w;
    }

    float accI[4] = {0.f, 0.f, 0.f, 0.f};
    float accJ[4] = {0.f, 0.f, 0.f, 0.f};

#pragma unroll
    for (int q = 0; q < 4; ++q) {
        const int j = j0 + jg * 4 + q;
        const float4* src = (const float4*)(M + (size_t)j * BC + b * CC);
        const float4 m0 = src[0], m1 = src[1], m2 = src[2], m3 = src[3];
        const float mj[CC] = {m0.x, m0.y, m0.z, m0.w, m1.x, m1.y, m1.z, m1.w,
                              m2.x, m2.y, m2.z, m2.w, m3.x, m3.y, m3.z, m3.w};
#pragma unroll
        for (int p = 0; p < 4; ++p) {
            float d0 = 0.f, d1 = 0.f, d2 = 0.f, d3 = 0.f;
#pragma unroll
            for (int c = 0; c < CC; c += 4) {
                d0 += fabsf(mj[c + 0] - mi[p][c + 0]);   // v_sub + v_add(abs-mod)
                d1 += fabsf(mj[c + 1] - mi[p][c + 1]);
                d2 += fabsf(mj[c + 2] - mi[p][c + 2]);
                d3 += fabsf(mj[c + 3] - mi[p][c + 3]);
            }
            const float c2 = __builtin_amdgcn_exp2f(-((d0 + d1) + (d2 + d3)));
            accI[p] += c2;
            accJ[q] += c2;
        }
    }

    __shared__ float redI[4][TR][32];
    __shared__ float redJ[4][TR][32];
#pragma unroll
    for (int p = 0; p < 4; ++p) redI[jg][ig * 4 + p][b] = accI[p];
    if (!diag) {
#pragma unroll
        for (int q = 0; q < 4; ++q) redJ[ig][jg * 4 + q][b] = accJ[q];
    }
    __syncthreads();

    const int rl = t >> 5;
    const int b2 = t & 31;
    {
        const float s = redI[0][rl][b2] + redI[1][rl][b2]
                      + redI[2][rl][b2] + redI[3][rl][b2];
        atomicAdd(out + (size_t)(i0 + rl) * OUTW + AA + b2, s);
    }
    if (!diag) {
        const float s = redJ[0][rl][b2] + redJ[1][rl][b2]
                      + redJ[2][rl][b2] + redJ[3][rl][b2];
        atomicAdd(out + (size_t)(j0 + rl) * OUTW + AA + b2, s);
    }
}

extern "C" void kernel_launch(void* const* d_in, const int* in_sizes, int n_in,
                              void* d_out, int out_size, void* d_ws, size_t ws_size,
                              hipStream_t stream) {
    const float* x = (const float*)d_in[0];  // (N, A)
    const float* T = (const float*)d_in[1];  // (A, B, C)
    float* out = (float*)d_out;              // (N, A+B)
    float* M   = (float*)d_ws;               // (N, B*C) scratch, 1 MiB

    gemm_kernel<<<256, 512, 0, stream>>>(x, T, M, out);
    pairwise_sym_kernel<<<NT * (NT + 1) / 2, 512, 0, stream>>>(M, out);
}